// Round 14
// baseline (76.039 us; speedup 1.0000x reference)
//
#include <hip/hip_runtime.h>
#include <stdint.h>

#define N_ROWS 4096
#define D_DIM  1024
#define N_CAND 8192
#define TEMP_INV 20.0f
#define QSCALE 508.0f
#define OUT_SCALE (TEMP_INV / (QSCALE * QSCALE))

#define BM 256
#define BN 256
#define BK 64
#define NT 16  // K-tiles

typedef __attribute__((ext_vector_type(4))) int i32x4;

using gvoid = __attribute__((address_space(1))) void;
using lvoid = __attribute__((address_space(3))) void;

#define BAR() __builtin_amdgcn_s_barrier()
#define SCHED0() __builtin_amdgcn_sched_barrier(0)

// ---------------------------------------------------------------------------
// Kernel 1: normalize rows, quantize to int8 (q = rint(x*508), clamp +-127),
// natural column order. cand = [P; N]. Also zeroes rowsum.
// ---------------------------------------------------------------------------
__global__ __launch_bounds__(256) void prep_kernel(
    const float* __restrict__ s, const float* __restrict__ p,
    const float* __restrict__ ng, unsigned char* __restrict__ s_q,
    unsigned char* __restrict__ cand_q, float* __restrict__ rowsum) {
  const int row = blockIdx.x;
  const int t = threadIdx.x;
  const float* src;
  unsigned char* dst;
  if (row < N_ROWS) {
    src = s + (size_t)row * D_DIM;
    dst = s_q + (size_t)row * D_DIM;
  } else if (row < 2 * N_ROWS) {
    src = p + (size_t)(row - N_ROWS) * D_DIM;
    dst = cand_q + (size_t)(row - N_ROWS) * D_DIM;
  } else {
    src = ng + (size_t)(row - 2 * N_ROWS) * D_DIM;
    dst = cand_q + (size_t)(row - N_ROWS) * D_DIM;
  }

  float4 v = reinterpret_cast<const float4*>(src)[t];
  float ss = v.x * v.x + v.y * v.y + v.z * v.z + v.w * v.w;
#pragma unroll
  for (int m = 32; m >= 1; m >>= 1) ss += __shfl_xor(ss, m, 64);
  __shared__ float red[4];
  const int w = t >> 6, l = t & 63;
  if (l == 0) red[w] = ss;
  __syncthreads();
  const float tot = red[0] + red[1] + red[2] + red[3];
  const float qs = QSCALE / fmaxf(sqrtf(tot), 1e-8f);

  auto q8 = [&](float x) -> unsigned {
    return (unsigned)((int)rintf(fminf(fmaxf(x * qs, -127.0f), 127.0f))) &
           0xffu;
  };
  const unsigned pk =
      q8(v.x) | (q8(v.y) << 8) | (q8(v.z) << 16) | (q8(v.w) << 24);
  *reinterpret_cast<unsigned*>(dst + t * 4) = pk;

  if (t == 0 && row < N_ROWS) rowsum[row] = 0.0f;
}

// ---------------------------------------------------------------------------
// Kernel 2: fused i8 GEMM + exp-rowsum. 256x256 tile, BK=64, 512 thr =
// 8 waves arranged 4M x 2N (wave 64x128 = 4x8 frags of mfma_i32_16x16x64_i8,
// acc in AGPRs -- the no-spill path).
// KEY CHANGE vs r13: A fragments have ZERO LDS reuse (each 16B slot is
// consumed by exactly one lane), so A loads go global->VGPR directly
// (L2-resident panel); LDS stages B ONLY: 4 x 16 KB ring = 64 KB ->
// 2 blocks/CU, 4 waves/SIMD. Per tile per wave: 4 vmem af + 2 stage DMA +
// 8 ds_read bf + 32 MFMA. Issue order af -> stage(T+2) -> bf lets the
// compiler's in-order vmcnt wait per m-group (vmcnt(5-m)), pipelining A
// latency under MFMA and keeping stage(T+2) in flight; explicit vmcnt(2)
// before the barrier guarantees tile T+1's B landed. LDS slot rotation
// phys=(g+(rl>>1))&3 (r7/r13-verified conflict-free).
// ---------------------------------------------------------------------------
__global__ __launch_bounds__(512) void gemm_lse_kernel(
    const unsigned char* __restrict__ s_q,
    const unsigned char* __restrict__ cand_q,
    float* __restrict__ rowsum, float* __restrict__ pos) {
  __shared__ __align__(16) unsigned char lds[4 * 16384];  // B only, 64 KB

  const int t = threadIdx.x;
  const int w = t >> 6;
  const int l = t & 63;
  const int g = l >> 4;    // k-slice group: lane's 16B = k g*16..g*16+15
  const int rl = l & 15;   // lane within group
  const int wm = w >> 1;   // 0..3 (wave M quarter, 64 rows)
  const int wn = w & 1;    // 0..1 (wave N half, 128 cols)
  const int slot = (g + (rl >> 1)) & 3;  // phys 16B-slot, lane-constant
  const int rowBase = blockIdx.y * BM;
  const int colBase = blockIdx.x * BN;

  i32x4 acc[4][8] = {};  // 128 AGPR
  i32x4 af[4];
  i32x4 bf[8];

  // A direct-load lane base: row = rowBase + wm*64 + m*16 + rl, k byte g*16.
  const unsigned char* gAf =
      s_q + (size_t)(rowBase + wm * 64 + rl) * D_DIM + g * 16;

  // B staging: thread t -> phys slot (t&3) of local row (t>>2), linear LDS
  // dst t*16; fetch logical slot = ((t&3) - (t>>3)) & 3  (r7-verified).
  const int sRow = t >> 2;                      // 0..127
  const int sSlotL = ((t & 3) - (t >> 3)) & 3;  // logical slot to fetch
  const unsigned char* gB =
      cand_q + (size_t)(colBase + sRow) * D_DIM + sSlotL * 16;

  auto stageB = [&](int T) {
    const int buf = (T & 3) * 16384;
    const size_t ko = (size_t)T * 64;
    __builtin_amdgcn_global_load_lds((const gvoid*)(gB + ko),
                                     (lvoid*)(lds + buf + t * 16), 16, 0, 0);
    __builtin_amdgcn_global_load_lds(
        (const gvoid*)(gB + ko + (size_t)128 * D_DIM),
        (lvoid*)(lds + buf + 8192 + t * 16), 16, 0, 0);
  };

  // --- prologue: stage B tiles 0,1; wait tile 0 (tile 1's 2 in flight).
  stageB(0); stageB(1);
  asm volatile("s_waitcnt vmcnt(2)" ::: "memory");
  SCHED0();
  BAR(); SCHED0();

  for (int T = 0; T < NT; ++T) {
    // A direct loads FIRST (so MFMA's af waits leave stage(T+2) in flight)
#pragma unroll
    for (int m = 0; m < 4; ++m)
      af[m] = *reinterpret_cast<const i32x4*>(
          gAf + (size_t)m * (16 * D_DIM) + T * 64);
    if (T + 2 < NT) stageB(T + 2);

    const unsigned char* B = lds + (T & 3) * 16384;
#pragma unroll
    for (int n = 0; n < 8; ++n) {
      const int r = wn * 128 + n * 16 + rl;
      bf[n] = *reinterpret_cast<const i32x4*>(B + r * 64 + slot * 16);
    }

    __builtin_amdgcn_s_setprio(1);
#pragma unroll
    for (int m = 0; m < 4; ++m)
#pragma unroll
      for (int n = 0; n < 8; ++n)
        acc[m][n] = __builtin_amdgcn_mfma_i32_16x16x64_i8(
            af[m], bf[n], acc[m][n], 0, 0, 0);
    __builtin_amdgcn_s_setprio(0);

    if (T + 2 < NT) {
      asm volatile("s_waitcnt vmcnt(2)" ::: "memory");  // T+1's B landed
    } else {
      asm volatile("s_waitcnt vmcnt(0)" ::: "memory");  // tail drain
    }
    SCHED0();
    BAR(); SCHED0();
  }

  // --- epilogue: sim = acc * 20/508^2; cosine<=1 -> fixed-max LSE at 20.
  // i32 16x16 C/D layout (dtype-independent): col = l&15, row = g*4 + reg.
  __syncthreads();
  float* red = reinterpret_cast<float*>(lds);
  if (t < BM) red[t] = 0.0f;
  __syncthreads();

#pragma unroll
  for (int m = 0; m < 4; ++m) {
#pragma unroll
    for (int j = 0; j < 4; ++j) {
      const int rloc = wm * 64 + m * 16 + g * 4 + j;
      const int rowg = rowBase + rloc;
      float sm = 0.0f;
#pragma unroll
      for (int n = 0; n < 8; ++n) {
        const int colg = colBase + wn * 128 + n * 16 + rl;
        const float simv = (float)acc[m][n][j] * OUT_SCALE;
        if (colg == rowg) pos[rowg] = simv;
        sm += __expf(simv - TEMP_INV);
      }
      sm += __shfl_xor(sm, 1, 64);
      sm += __shfl_xor(sm, 2, 64);
      sm += __shfl_xor(sm, 4, 64);
      sm += __shfl_xor(sm, 8, 64);
      if (rl == 0) atomicAdd(&red[rloc], sm);
    }
  }
  __syncthreads();
  if (t < BM) atomicAdd(&rowsum[rowBase + t], red[t]);
}

// ---------------------------------------------------------------------------
// Kernel 3: loss = mean(20 + log(rowsum) - pos)
// ---------------------------------------------------------------------------
__global__ __launch_bounds__(1024) void loss_kernel(
    const float* __restrict__ rowsum, const float* __restrict__ pos,
    float* __restrict__ out) {
  const int t = threadIdx.x;
  float acc = 0.0f;
  for (int i = t; i < N_ROWS; i += 1024)
    acc += TEMP_INV + logf(rowsum[i]) - pos[i];
#pragma unroll
  for (int m = 32; m >= 1; m >>= 1) acc += __shfl_xor(acc, m, 64);
  __shared__ float red[16];
  const int w = t >> 6, l = t & 63;
  if (l == 0) red[w] = acc;
  __syncthreads();
  if (t == 0) {
    float tot = 0.0f;
#pragma unroll
    for (int i = 0; i < 16; ++i) tot += red[i];
    out[0] = tot / (float)N_ROWS;
  }
}

// ---------------------------------------------------------------------------
extern "C" void kernel_launch(void* const* d_in, const int* in_sizes, int n_in,
                              void* d_out, int out_size, void* d_ws,
                              size_t ws_size, hipStream_t stream) {
  (void)in_sizes; (void)n_in; (void)out_size; (void)ws_size;
  const float* s = (const float*)d_in[0];
  const float* p = (const float*)d_in[1];
  const float* ng = (const float*)d_in[2];

  unsigned char* s_q = (unsigned char*)d_ws;                      // 4 MB
  unsigned char* cand_q = s_q + (size_t)N_ROWS * D_DIM;           // 8 MB
  float* rowsum = (float*)(cand_q + (size_t)N_CAND * D_DIM);      // 16 KB
  float* pos = rowsum + N_ROWS;                                   // 16 KB
  float* out = (float*)d_out;

  prep_kernel<<<dim3(3 * N_ROWS), dim3(256), 0, stream>>>(s, p, ng, s_q,
                                                          cand_q, rowsum);
  gemm_lse_kernel<<<dim3(N_CAND / BN, N_ROWS / BM), dim3(512), 0, stream>>>(
      s_q, cand_q, rowsum, pos);
  loss_kernel<<<dim3(1), dim3(1024), 0, stream>>>(rowsum, pos, out);
}